// Round 2
// baseline (776.851 us; speedup 1.0000x reference)
//
#include <hip/hip_runtime.h>

typedef unsigned short u16;
typedef unsigned int   u32;
typedef __bf16 bf16_t;
typedef bf16_t bf16x8 __attribute__((ext_vector_type(8)));
typedef float  f32x4  __attribute__((ext_vector_type(4)));

__device__ __forceinline__ float b2f(u16 u){
  u32 x = ((u32)u) << 16;
  return __builtin_bit_cast(float, x);
}
__device__ __forceinline__ u16 f2b(float f){
  u32 u = __builtin_bit_cast(u32, f);
  u32 r = u + 0x7FFFu + ((u >> 16) & 1u);   // round-to-nearest-even
  return (u16)(r >> 16);
}

union V8 { uint4 q; u16 u[8]; };

// ---------- transpose + f32->bf16 convert: src[512][nc] f32 -> dst[nc][512] bf16 ----------
struct TArgs {
  const float* src[9];
  u16* dst[9];
  int ncol[9];
};

__global__ __launch_bounds__(256) void transpose_k(TArgs t){
  int z = blockIdx.z;
  int nc = t.ncol[z];
  int j0 = blockIdx.y * 64;
  if (j0 >= nc) return;
  int i0 = blockIdx.x * 64;
  __shared__ u16 T[64][65];
  const float* s = t.src[z];
  u16* d = t.dst[z];
  #pragma unroll
  for (int rep = 0; rep < 16; rep++){
    int lin = rep*256 + threadIdx.x;
    int r = lin >> 6, c = lin & 63;
    T[c][r] = f2b(s[(size_t)(i0 + r) * nc + j0 + c]);
  }
  __syncthreads();
  #pragma unroll
  for (int rep = 0; rep < 16; rep++){
    int lin = rep*256 + threadIdx.x;
    int r = lin >> 6, c = lin & 63;
    d[(size_t)(j0 + r) * 512 + i0 + c] = T[r][c];
  }
}

// ---------------- MFMA GEMM, 128x128 tile, BK=32, 4 waves 2x2 (64x64 each) ----------------
// MODE 0: C(bf16) = A0f(f32) @ B + bias                          (K=512,  N=512) -> proj raw
// MODE 1: C(bf16) = sum_w (G_w ⊙ k_src_w) @ p_w + Σp_b + qI + qM (K=2048, N=512) -> mid
// MODE 2: C(f32)  = A0h(bf16) @ fT^T + f_b                       (K=512,  N=256) -> out
template<int MODE>
__global__ __launch_bounds__(256) void gemm_k(
    const float* __restrict__ A0f, const u16* __restrict__ A0h,
    const u16* __restrict__ AkI, const u16* __restrict__ AkM,
    const u16* __restrict__ BT,
    const float* __restrict__ bias0,
    const float* __restrict__ pb1, const float* __restrict__ pb2,
    const float* __restrict__ pb3, const float* __restrict__ pb4,
    const u16* __restrict__ qI, const u16* __restrict__ qM,
    const float* __restrict__ G,
    u16* __restrict__ Ch, float* __restrict__ Cf, int ldc)
{
  const int tid = threadIdx.x;
  const int m0 = blockIdx.x * 128;
  const int n0 = blockIdx.y * 128;
  constexpr int KTOT = (MODE == 1) ? 2048 : 512;
  __shared__ u16 As[128*40];   // stride 40 elems = 80B (16B aligned; 2-way bank alias = free)
  __shared__ u16 Bs[128*40];
  f32x4 acc[4][4] = {};
  const int l = tid & 63, w = tid >> 6;
  const int wm = (w >> 1) * 64, wn = (w & 1) * 64;
  const int lr = l & 15, quad = l >> 4;
  const int lrow = tid >> 1;         // 0..127 tile row (bf16 staging path)
  const int lseg = (tid & 1) * 16;   // elem offset in 32-wide k slab
  const int frow = tid >> 2;         // 0..63 (f32 staging path, 2 reps)
  const int fseg = (tid & 3) * 8;    // 8 f32 elems = 32B contiguous per lane
  const int bb = m0 >> 12;           // batch index (4096 rows per batch)

  for (int k0 = 0; k0 < KTOT; k0 += 32){
    __syncthreads();
    // ---- stage A tile (128 rows x 32 k) ----
    if constexpr (MODE == 0){
      #pragma unroll
      for (int rep = 0; rep < 2; rep++){
        int row = rep*64 + frow;
        const float* src = A0f + (size_t)(m0 + row) * 512 + k0 + fseg;
        float4 p0 = *(const float4*)src;
        float4 p1 = *(const float4*)(src + 4);
        V8 O;
        O.u[0]=f2b(p0.x); O.u[1]=f2b(p0.y); O.u[2]=f2b(p0.z); O.u[3]=f2b(p0.w);
        O.u[4]=f2b(p1.x); O.u[5]=f2b(p1.y); O.u[6]=f2b(p1.z); O.u[7]=f2b(p1.w);
        *(uint4*)&As[row*40 + fseg] = O.q;
      }
    } else if constexpr (MODE == 1){
      int which = k0 >> 9;
      int kloc = k0 & 511;
      const u16* ksrc = (which == 0 || which == 3) ? AkI : AkM;
      const float* gp = G + ((which < 2) ? 0 : 4096) + bb * 512 + kloc + lseg;
      const u16* src = ksrc + (size_t)(m0 + lrow) * 512 + kloc + lseg;
      V8 P0, P1, O0, O1;
      P0.q = *(const uint4*)src;
      P1.q = *(const uint4*)(src + 8);
      #pragma unroll
      for (int j = 0; j < 8; j++){
        O0.u[j] = f2b(b2f(P0.u[j]) * gp[j]);
        O1.u[j] = f2b(b2f(P1.u[j]) * gp[j + 8]);
      }
      *(uint4*)&As[lrow*40 + lseg]     = O0.q;
      *(uint4*)&As[lrow*40 + lseg + 8] = O1.q;
    } else {
      const u16* src = A0h + (size_t)(m0 + lrow) * 512 + k0 + lseg;
      uint4 p0 = *(const uint4*)src;
      uint4 p1 = *(const uint4*)(src + 8);
      *(uint4*)&As[lrow*40 + lseg]     = p0;
      *(uint4*)&As[lrow*40 + lseg + 8] = p1;
    }
    // ---- stage B^T tile (128 n x 32 k), bf16 source always ----
    {
      const u16* src;
      if constexpr (MODE == 1){
        int which = k0 >> 9;
        int kloc = k0 & 511;
        src = BT + (size_t)which * 262144 + (size_t)(n0 + lrow) * 512 + kloc + lseg;
      } else {
        src = BT + (size_t)(n0 + lrow) * 512 + k0 + lseg;
      }
      uint4 q0 = *(const uint4*)src;
      uint4 q1 = *(const uint4*)(src + 8);
      *(uint4*)&Bs[lrow*40 + lseg]     = q0;
      *(uint4*)&Bs[lrow*40 + lseg + 8] = q1;
    }
    __syncthreads();
    // ---- 16 MFMAs ----
    bf16x8 aF[4], bF[4];
    #pragma unroll
    for (int mt = 0; mt < 4; mt++)
      aF[mt] = *(const bf16x8*)&As[(wm + mt*16 + lr)*40 + quad*8];
    #pragma unroll
    for (int nt = 0; nt < 4; nt++)
      bF[nt] = *(const bf16x8*)&Bs[(wn + nt*16 + lr)*40 + quad*8];
    #pragma unroll
    for (int mt = 0; mt < 4; mt++){
      #pragma unroll
      for (int nt = 0; nt < 4; nt++)
        acc[mt][nt] = __builtin_amdgcn_mfma_f32_16x16x32_bf16(aF[mt], bF[nt], acc[mt][nt], 0, 0, 0);
    }
  }
  // ---- epilogue: C/D layout row = quad*4 + r, col = lane&15 ----
  #pragma unroll
  for (int nt = 0; nt < 4; nt++){
    int col = n0 + wn + nt*16 + lr;
    float addc;
    if constexpr (MODE == 1)
      addc = pb1[col] + pb2[col] + pb3[col] + pb4[col];
    else
      addc = bias0[col];
    #pragma unroll
    for (int mt = 0; mt < 4; mt++){
      int row0 = m0 + wm + mt*16 + quad*4;
      #pragma unroll
      for (int r = 0; r < 4; r++){
        float val = acc[mt][nt][r] + addc;
        size_t idx = (size_t)(row0 + r) * ldc + col;
        if constexpr (MODE == 1){
          size_t qidx = (size_t)(row0 + r) * 512 + col;
          val += b2f(qI[qidx]) + b2f(qM[qidx]);
          Ch[idx] = f2b(val);
        } else if constexpr (MODE == 0){
          Ch[idx] = f2b(val);
        } else {
          Cf[idx] = val;
        }
      }
    }
  }
}

// -------- row l2norm (in place, bf16) + A_raw = (qnorm . wg) * SCALE --------
__global__ __launch_bounds__(256) void rownorm_k(
    u16* __restrict__ qI, u16* __restrict__ kI, u16* __restrict__ qM, u16* __restrict__ kM,
    const float* __restrict__ wgI, const float* __restrict__ wgM,
    float* __restrict__ Araw)
{
  int y = blockIdx.y;                       // 0:qI 1:kI 2:qM 3:kM
  int w = threadIdx.x >> 6, l = threadIdx.x & 63;
  int row = blockIdx.x * 4 + w;
  u16* base = (y == 0) ? qI : (y == 1) ? kI : (y == 2) ? qM : kM;
  u16* Y = base + (size_t)row * 512;
  V8 P; P.q = *(uint4*)&Y[l*8];
  float v[8]; float ss = 0.f;
  #pragma unroll
  for (int j = 0; j < 8; j++){ v[j] = b2f(P.u[j]); ss += v[j]*v[j]; }
  #pragma unroll
  for (int off = 32; off > 0; off >>= 1) ss += __shfl_xor(ss, off, 64);
  float rn = 1.f / fmaxf(sqrtf(ss), 1e-12f);
  V8 O;
  #pragma unroll
  for (int j = 0; j < 8; j++){ v[j] *= rn; O.u[j] = f2b(v[j]); }
  *(uint4*)&Y[l*8] = O.q;
  if (y == 0 || y == 2){
    const float* wg = (y == 0) ? wgI : wgM;
    float4 W0 = *(const float4*)&wg[l*8];
    float4 W1 = *(const float4*)&wg[l*8 + 4];
    float dot = v[0]*W0.x + v[1]*W0.y + v[2]*W0.z + v[3]*W0.w
              + v[4]*W1.x + v[5]*W1.y + v[6]*W1.z + v[7]*W1.w;
    #pragma unroll
    for (int off = 32; off > 0; off >>= 1) dot += __shfl_xor(dot, off, 64);
    if (l == 0) Araw[((y == 0) ? 0 : 1) * 32768 + row] = dot * 0.0625f;  // SCALE = 1/16
  }
}

// ---------------- per-batch 1/||A|| over N, and zero G ----------------
__global__ __launch_bounds__(256) void anorm_k(const float* __restrict__ Araw,
                                               float* __restrict__ rA, float* __restrict__ G){
  int b = blockIdx.x, wsel = blockIdx.y;
  const float* A = Araw + wsel*32768 + b*4096;
  float ss = 0.f;
  for (int i = threadIdx.x; i < 4096; i += 256){ float a = A[i]; ss += a*a; }
  #pragma unroll
  for (int off = 32; off > 0; off >>= 1) ss += __shfl_xor(ss, off, 64);
  __shared__ float red[4];
  if ((threadIdx.x & 63) == 0) red[threadIdx.x >> 6] = ss;
  __syncthreads();
  if (threadIdx.x == 0){
    float t = red[0] + red[1] + red[2] + red[3];
    rA[wsel*8 + b] = 1.f / fmaxf(sqrtf(t), 1e-12f);
  }
  G[(wsel*8 + b)*512 + threadIdx.x] = 0.f;
  G[(wsel*8 + b)*512 + threadIdx.x + 256] = 0.f;
}

// ---------------- G[b,d] = sum_n A_norm[b,n] * q[b,n,d] ----------------
__global__ __launch_bounds__(256) void gcalc_k(const u16* __restrict__ qI, const u16* __restrict__ qM,
                                               const float* __restrict__ Araw,
                                               const float* __restrict__ rA,
                                               float* __restrict__ G){
  int chunk = blockIdx.x, b = blockIdx.y, wsel = blockIdx.z;
  const u16* q = (wsel == 0) ? qI : qM;
  float r = rA[wsel*8 + b];
  __shared__ float Ash[512];
  int n0 = chunk * 512;
  Ash[threadIdx.x]       = Araw[wsel*32768 + b*4096 + n0 + threadIdx.x] * r;
  Ash[threadIdx.x + 256] = Araw[wsel*32768 + b*4096 + n0 + threadIdx.x + 256] * r;
  __syncthreads();
  float a0 = 0.f, a1 = 0.f;
  for (int n = 0; n < 512; n++){
    float av = Ash[n];
    const u16* qr = q + (size_t)(b*4096 + n0 + n) * 512;
    a0 += av * b2f(qr[threadIdx.x]);
    a1 += av * b2f(qr[threadIdx.x + 256]);
  }
  atomicAdd(&G[(wsel*8 + b)*512 + threadIdx.x], a0);
  atomicAdd(&G[(wsel*8 + b)*512 + threadIdx.x + 256], a1);
}

extern "C" void kernel_launch(void* const* d_in, const int* in_sizes, int n_in,
                              void* d_out, int out_size, void* d_ws, size_t ws_size,
                              hipStream_t stream)
{
  const float* x_I  = (const float*)d_in[0];
  const float* x_M  = (const float*)d_in[1];
  const float* wq_I = (const float*)d_in[2];
  const float* bq_I = (const float*)d_in[3];
  const float* wk_I = (const float*)d_in[4];
  const float* bk_I = (const float*)d_in[5];
  const float* wq_M = (const float*)d_in[6];
  const float* bq_M = (const float*)d_in[7];
  const float* wk_M = (const float*)d_in[8];
  const float* bk_M = (const float*)d_in[9];
  const float* wg_I = (const float*)d_in[10];
  const float* wg_M = (const float*)d_in[11];
  const float* p1_w = (const float*)d_in[12];
  const float* p1_b = (const float*)d_in[13];
  const float* p2_w = (const float*)d_in[14];
  const float* p2_b = (const float*)d_in[15];
  const float* p3_w = (const float*)d_in[16];
  const float* p3_b = (const float*)d_in[17];
  const float* p4_w = (const float*)d_in[18];
  const float* p4_b = (const float*)d_in[19];
  const float* f_w  = (const float*)d_in[20];
  const float* f_b  = (const float*)d_in[21];

  char* ws = (char*)d_ws;
  u16* wTqI  = (u16*)(ws + 0);
  u16* wTkI  = (u16*)(ws + 524288);
  u16* wTqM  = (u16*)(ws + 1048576);
  u16* wTkM  = (u16*)(ws + 1572864);
  u16* pTcat = (u16*)(ws + 2097152);   // [4][512][512] bf16
  u16* fT    = (u16*)(ws + 4194304);   // [256][512] bf16
  u16* qIb   = (u16*)(ws + 4456448);   // [32768][512] bf16 each
  u16* kIb   = (u16*)(ws + 38010880);
  u16* qMb   = (u16*)(ws + 71565312);
  u16* kMb   = (u16*)(ws + 105119744);
  u16* mid   = (u16*)(ws + 138674176);
  float* Araw = (float*)(ws + 172228608);  // [2][32768] f32
  float* rA   = (float*)(ws + 172490752);  // [2][8]
  float* G    = (float*)(ws + 172491008);  // [2][8][512] f32

  TArgs t;
  const float* srcs[9] = {wq_I, wk_I, wq_M, wk_M, p1_w, p2_w, p3_w, p4_w, f_w};
  u16* dsts[9] = {wTqI, wTkI, wTqM, wTkM,
                  pTcat, pTcat + 262144, pTcat + 524288, pTcat + 786432, fT};
  for (int i = 0; i < 9; i++){ t.src[i] = srcs[i]; t.dst[i] = dsts[i]; t.ncol[i] = (i == 8) ? 256 : 512; }

  transpose_k<<<dim3(8,8,9), 256, 0, stream>>>(t);

  gemm_k<0><<<dim3(256,4), 256, 0, stream>>>(x_I, nullptr, nullptr, nullptr, wTqI, bq_I,
      nullptr, nullptr, nullptr, nullptr, nullptr, nullptr, nullptr, qIb, nullptr, 512);
  gemm_k<0><<<dim3(256,4), 256, 0, stream>>>(x_I, nullptr, nullptr, nullptr, wTkI, bk_I,
      nullptr, nullptr, nullptr, nullptr, nullptr, nullptr, nullptr, kIb, nullptr, 512);
  gemm_k<0><<<dim3(256,4), 256, 0, stream>>>(x_M, nullptr, nullptr, nullptr, wTqM, bq_M,
      nullptr, nullptr, nullptr, nullptr, nullptr, nullptr, nullptr, qMb, nullptr, 512);
  gemm_k<0><<<dim3(256,4), 256, 0, stream>>>(x_M, nullptr, nullptr, nullptr, wTkM, bk_M,
      nullptr, nullptr, nullptr, nullptr, nullptr, nullptr, nullptr, kMb, nullptr, 512);

  rownorm_k<<<dim3(8192,4), 256, 0, stream>>>(qIb, kIb, qMb, kMb, wg_I, wg_M, Araw);
  anorm_k<<<dim3(8,2), 256, 0, stream>>>(Araw, rA, G);
  gcalc_k<<<dim3(8,8,2), 256, 0, stream>>>(qIb, qMb, Araw, rA, G);

  gemm_k<1><<<dim3(256,4), 256, 0, stream>>>(nullptr, nullptr, kIb, kMb, pTcat, nullptr,
      p1_b, p2_b, p3_b, p4_b, qIb, qMb, G, mid, nullptr, 512);
  gemm_k<2><<<dim3(256,2), 256, 0, stream>>>(nullptr, mid, nullptr, nullptr, fT, f_b,
      nullptr, nullptr, nullptr, nullptr, nullptr, nullptr, nullptr, nullptr, (float*)d_out, 256);
}

// Round 4
// 499.556 us; speedup vs baseline: 1.5551x; 1.5551x over previous
//
#include <hip/hip_runtime.h>

typedef unsigned short u16;
typedef unsigned int   u32;
typedef __bf16 bf16_t;
typedef bf16_t bf16x8 __attribute__((ext_vector_type(8)));
typedef float  f32x4  __attribute__((ext_vector_type(4)));

__device__ __forceinline__ float b2f(u16 u){
  u32 x = ((u32)u) << 16;
  return __builtin_bit_cast(float, x);
}
__device__ __forceinline__ u16 f2b(float f){
  u32 u = __builtin_bit_cast(u32, f);
  u32 r = u + 0x7FFFu + ((u >> 16) & 1u);   // round-to-nearest-even
  return (u16)(r >> 16);
}

union V8 { uint4 q; u16 u[8]; };

// async global(16B/lane) -> LDS. dst must be wave-uniform; lane l lands at dst + l*16B.
__device__ __forceinline__ void gld16(const u16* gsrc, u16* ldst){
  __builtin_amdgcn_global_load_lds(
      (const __attribute__((address_space(1))) u32*)gsrc,
      (__attribute__((address_space(3))) u32*)ldst, 16, 0, 0);
}

// ---------- straight f32 -> bf16 convert (x_I, x_M, p1..p4) ----------
struct CArgs { const float* src[6]; u16* dst[6]; int cnt[6]; };

__global__ __launch_bounds__(256) void convert_k(CArgs c){
  int z = blockIdx.z;
  int i8 = (blockIdx.x * 256 + threadIdx.x) * 8;
  if (i8 >= c.cnt[z]) return;
  const float* s = c.src[z] + i8;
  float4 a = *(const float4*)s;
  float4 b = *(const float4*)(s + 4);
  V8 o;
  o.u[0]=f2b(a.x); o.u[1]=f2b(a.y); o.u[2]=f2b(a.z); o.u[3]=f2b(a.w);
  o.u[4]=f2b(b.x); o.u[5]=f2b(b.y); o.u[6]=f2b(b.z); o.u[7]=f2b(b.w);
  *(uint4*)(c.dst[z] + i8) = o.q;
}

// ---------- transpose + convert: src[512][nc] f32 -> dst[nc][512] bf16 ----------
struct TArgs { const float* src[5]; u16* dst[5]; int ncol[5]; };

__global__ __launch_bounds__(256) void transpose_k(TArgs t){
  int z = blockIdx.z;
  int nc = t.ncol[z];
  int j0 = blockIdx.y * 64;
  if (j0 >= nc) return;
  int i0 = blockIdx.x * 64;
  __shared__ u16 T[64][65];
  const float* s = t.src[z];
  u16* d = t.dst[z];
  #pragma unroll
  for (int rep = 0; rep < 16; rep++){
    int lin = rep*256 + threadIdx.x;
    int r = lin >> 6, c = lin & 63;
    T[c][r] = f2b(s[(size_t)(i0 + r) * nc + j0 + c]);
  }
  __syncthreads();
  #pragma unroll
  for (int rep = 0; rep < 16; rep++){
    int lin = rep*256 + threadIdx.x;
    int r = lin >> 6, c = lin & 63;
    d[(size_t)(j0 + r) * 512 + i0 + c] = T[r][c];
  }
}

// ---------- cb[o] = (p1_b+p2_b+p3_b+p4_b) @ f_w + f_b ----------
__global__ __launch_bounds__(256) void cbias_k(
    const float* __restrict__ p1b, const float* __restrict__ p2b,
    const float* __restrict__ p3b, const float* __restrict__ p4b,
    const float* __restrict__ fw, const float* __restrict__ fb,
    float* __restrict__ cb)
{
  __shared__ float s[512];
  int tid = threadIdx.x;
  s[tid]       = p1b[tid] + p2b[tid] + p3b[tid] + p4b[tid];
  s[tid + 256] = p1b[tid+256] + p2b[tid+256] + p3b[tid+256] + p4b[tid+256];
  __syncthreads();
  float acc = 0.f;
  for (int j = 0; j < 512; j++) acc += s[j] * fw[j*256 + tid];
  cb[tid] = acc + fb[tid];
}

// ------------- MFMA GEMM, 128x128 tile, BK=32, global_load_lds staging -------------
// MODE 0 (PROJ):  C = A0 @ BT^T + [bq|bk]   K=512,  N=1024 -> Cq cols 0..511, Ck cols 512..1023 (bf16)
// MODE 1 (SMALL): C = A0 @ BT^T             K=512,  N=512  -> Cq (bf16)  [pfT build]
// MODE 2 (FINAL): C = [kI|kM|qI|qM] @ WT[b]^T + cb  K=2048, N=256 -> Cf (f32)
template<int MODE>
__global__ __launch_bounds__(256) void gemm2_k(
    const u16* __restrict__ A0, const u16* __restrict__ A1,
    const u16* __restrict__ A2, const u16* __restrict__ A3,
    const u16* __restrict__ BT,
    const float* __restrict__ bq, const float* __restrict__ bk,
    const float* __restrict__ cb,
    u16* __restrict__ Cq, u16* __restrict__ Ck, float* __restrict__ Cf)
{
  constexpr int KTOT = (MODE == 2) ? 2048 : 512;
  const int tid = threadIdx.x, l = tid & 63, w = tid >> 6;
  const int m0 = blockIdx.x * 128, n0 = blockIdx.y * 128;
  __shared__ u16 As[128*32];   // unpadded: required by global_load_lds lane layout
  __shared__ u16 Bs[128*32];
  f32x4 acc[4][4] = {};
  const int wm = (w >> 1) * 64, wn = (w & 1) * 64;
  const int lr = l & 15, quad = l >> 4;
  const int srow = l >> 2;          // 0..15 within a 16-row slab
  const int scol = (l & 3) * 8;     // 8 bf16 = 16 B per lane

  const u16* Bbase = BT;
  if constexpr (MODE == 2)
    Bbase = BT + (size_t)(m0 >> 12) * 256 * 2048;   // per-batch folded weights

  for (int k0 = 0; k0 < KTOT; k0 += 32){
    __syncthreads();
    const u16* Ab; int kloc;
    if constexpr (MODE == 2){
      int which = k0 >> 9; kloc = k0 & 511;
      Ab = (which == 0) ? A0 : (which == 1) ? A1 : (which == 2) ? A2 : A3;
    } else { Ab = A0; kloc = k0; }
    #pragma unroll
    for (int i = 0; i < 2; i++){
      int r = w*32 + i*16 + srow;
      gld16(Ab    + (size_t)(m0 + r) * 512  + kloc + scol, &As[(w*2 + i) * 512]);
      gld16(Bbase + (size_t)(n0 + r) * KTOT + k0   + scol, &Bs[(w*2 + i) * 512]);
    }
    __syncthreads();   // compiler emits vmcnt(0) drain here -> LDS valid
    bf16x8 aF[4], bF[4];
    #pragma unroll
    for (int mt = 0; mt < 4; mt++)
      aF[mt] = *(const bf16x8*)&As[(wm + mt*16 + lr)*32 + quad*8];
    #pragma unroll
    for (int nt = 0; nt < 4; nt++)
      bF[nt] = *(const bf16x8*)&Bs[(wn + nt*16 + lr)*32 + quad*8];
    #pragma unroll
    for (int mt = 0; mt < 4; mt++){
      #pragma unroll
      for (int nt = 0; nt < 4; nt++)
        acc[mt][nt] = __builtin_amdgcn_mfma_f32_16x16x32_bf16(aF[mt], bF[nt], acc[mt][nt], 0, 0, 0);
    }
  }
  // epilogue: C/D layout row = quad*4 + r, col = lane&15
  #pragma unroll
  for (int nt = 0; nt < 4; nt++){
    int col = n0 + wn + nt*16 + lr;
    #pragma unroll
    for (int mt = 0; mt < 4; mt++){
      int row0 = m0 + wm + mt*16 + quad*4;
      #pragma unroll
      for (int r = 0; r < 4; r++){
        int row = row0 + r;
        float v = acc[mt][nt][r];
        if constexpr (MODE == 0){
          if (col < 512) Cq[(size_t)row*512 + col]         = f2b(v + bq[col]);
          else           Ck[(size_t)row*512 + (col - 512)] = f2b(v + bk[col - 512]);
        } else if constexpr (MODE == 1){
          Cq[(size_t)row*512 + col] = f2b(v);
        } else {
          Cf[(size_t)row*256 + col] = v + cb[col];
        }
      }
    }
  }
}

// -------- row l2norm (in place, bf16) + A_raw = (qnorm . wg) * SCALE --------
__global__ __launch_bounds__(256) void rownorm_k(
    u16* __restrict__ qI, u16* __restrict__ kI, u16* __restrict__ qM, u16* __restrict__ kM,
    const float* __restrict__ wgI, const float* __restrict__ wgM,
    float* __restrict__ Araw)
{
  int y = blockIdx.y;                       // 0:qI 1:kI 2:qM 3:kM
  int w = threadIdx.x >> 6, l = threadIdx.x & 63;
  int row = blockIdx.x * 4 + w;
  u16* base = (y == 0) ? qI : (y == 1) ? kI : (y == 2) ? qM : kM;
  u16* Y = base + (size_t)row * 512;
  V8 P; P.q = *(uint4*)&Y[l*8];
  float v[8]; float ss = 0.f;
  #pragma unroll
  for (int j = 0; j < 8; j++){ v[j] = b2f(P.u[j]); ss += v[j]*v[j]; }
  #pragma unroll
  for (int off = 32; off > 0; off >>= 1) ss += __shfl_xor(ss, off, 64);
  float rn = 1.f / fmaxf(sqrtf(ss), 1e-12f);
  V8 O;
  #pragma unroll
  for (int j = 0; j < 8; j++){ v[j] *= rn; O.u[j] = f2b(v[j]); }
  *(uint4*)&Y[l*8] = O.q;
  if (y == 0 || y == 2){
    const float* wg = (y == 0) ? wgI : wgM;
    float4 W0 = *(const float4*)&wg[l*8];
    float4 W1 = *(const float4*)&wg[l*8 + 4];
    float dot = v[0]*W0.x + v[1]*W0.y + v[2]*W0.z + v[3]*W0.w
              + v[4]*W1.x + v[5]*W1.y + v[6]*W1.z + v[7]*W1.w;
    #pragma unroll
    for (int off = 32; off > 0; off >>= 1) dot += __shfl_xor(dot, off, 64);
    if (l == 0) Araw[((y == 0) ? 0 : 1) * 32768 + row] = dot * 0.0625f;  // SCALE = 1/16
  }
}

// ---------------- per-batch 1/||A|| over N, and zero G ----------------
__global__ __launch_bounds__(256) void anorm_k(const float* __restrict__ Araw,
                                               float* __restrict__ rA, float* __restrict__ G){
  int b = blockIdx.x, wsel = blockIdx.y;
  const float* A = Araw + wsel*32768 + b*4096;
  float ss = 0.f;
  for (int i = threadIdx.x; i < 4096; i += 256){ float a = A[i]; ss += a*a; }
  #pragma unroll
  for (int off = 32; off > 0; off >>= 1) ss += __shfl_xor(ss, off, 64);
  __shared__ float red[4];
  if ((threadIdx.x & 63) == 0) red[threadIdx.x >> 6] = ss;
  __syncthreads();
  if (threadIdx.x == 0){
    float t = red[0] + red[1] + red[2] + red[3];
    rA[wsel*8 + b] = 1.f / fmaxf(sqrtf(t), 1e-12f);
  }
  G[(wsel*8 + b)*512 + threadIdx.x] = 0.f;
  G[(wsel*8 + b)*512 + threadIdx.x + 256] = 0.f;
}

// ---------------- G[b,d] = sum_n A_norm[b,n] * q[b,n,d] ----------------
__global__ __launch_bounds__(256) void gcalc_k(const u16* __restrict__ qI, const u16* __restrict__ qM,
                                               const float* __restrict__ Araw,
                                               const float* __restrict__ rA,
                                               float* __restrict__ G){
  int chunk = blockIdx.x, b = blockIdx.y, wsel = blockIdx.z;
  int tid = threadIdx.x;
  const u16* q = (wsel == 0) ? qI : qM;
  __shared__ float Ash[256];
  int n0 = chunk * 256;
  Ash[tid] = Araw[wsel*32768 + b*4096 + n0 + tid] * rA[wsel*8 + b];
  __syncthreads();
  const u16* qp = q + (size_t)(b*4096 + n0) * 512 + tid*2;
  float a0 = 0.f, a1 = 0.f;
  for (int n = 0; n < 256; n++){
    u32 pr = *(const u32*)(qp + (size_t)n * 512);
    float av = Ash[n];
    a0 += av * b2f((u16)(pr & 0xFFFF));
    a1 += av * b2f((u16)(pr >> 16));
  }
  atomicAdd(&G[(wsel*8 + b)*512 + tid*2],     a0);
  atomicAdd(&G[(wsel*8 + b)*512 + tid*2 + 1], a1);
}

// -------- WT[b][o][k]: k<512: G_I.pf1+G_M.pf4 (kI) ; <1024: G_I.pf2+G_M.pf3 (kM); else fT (qI+qM) --------
// pfT slabs are 256*512 = 131072 elements each.
__global__ __launch_bounds__(256) void weff_k(
    const u16* __restrict__ pfT, const u16* __restrict__ fT,
    const float* __restrict__ G, u16* __restrict__ WT)
{
  int b = blockIdx.x, o = blockIdx.y, tid = threadIdx.x;
  int k0 = tid * 8;
  V8 out;
  if (k0 < 1024){
    int kk = k0 & 511;
    const u16* pa = pfT + ((k0 < 512) ? 0      : 131072) + o*512 + kk;  // pf1 / pf2
    const u16* pb = pfT + ((k0 < 512) ? 393216 : 262144) + o*512 + kk;  // pf4 / pf3
    const float* gI = G + b*512 + kk;
    const float* gM = G + 4096 + b*512 + kk;
    V8 Pa, Pb; Pa.q = *(const uint4*)pa; Pb.q = *(const uint4*)pb;
    float4 gi0 = *(const float4*)gI, gi1 = *(const float4*)(gI+4);
    float4 gm0 = *(const float4*)gM, gm1 = *(const float4*)(gM+4);
    float gi[8] = {gi0.x,gi0.y,gi0.z,gi0.w,gi1.x,gi1.y,gi1.z,gi1.w};
    float gm[8] = {gm0.x,gm0.y,gm0.z,gm0.w,gm1.x,gm1.y,gm1.z,gm1.w};
    #pragma unroll
    for (int j = 0; j < 8; j++)
      out.u[j] = f2b(gi[j]*b2f(Pa.u[j]) + gm[j]*b2f(Pb.u[j]));
  } else {
    out.q = *(const uint4*)(fT + o*512 + (k0 & 511));
  }
  *(uint4*)(WT + ((size_t)b*256 + o)*2048 + k0) = out.q;
}

extern "C" void kernel_launch(void* const* d_in, const int* in_sizes, int n_in,
                              void* d_out, int out_size, void* d_ws, size_t ws_size,
                              hipStream_t stream)
{
  const float* x_I  = (const float*)d_in[0];
  const float* x_M  = (const float*)d_in[1];
  const float* wq_I = (const float*)d_in[2];
  const float* bq_I = (const float*)d_in[3];
  const float* wk_I = (const float*)d_in[4];
  const float* bk_I = (const float*)d_in[5];
  const float* wq_M = (const float*)d_in[6];
  const float* bq_M = (const float*)d_in[7];
  const float* wk_M = (const float*)d_in[8];
  const float* bk_M = (const float*)d_in[9];
  const float* wg_I = (const float*)d_in[10];
  const float* wg_M = (const float*)d_in[11];
  const float* p1_w = (const float*)d_in[12];
  const float* p1_b = (const float*)d_in[13];
  const float* p2_w = (const float*)d_in[14];
  const float* p2_b = (const float*)d_in[15];
  const float* p3_w = (const float*)d_in[16];
  const float* p3_b = (const float*)d_in[17];
  const float* p4_w = (const float*)d_in[18];
  const float* p4_b = (const float*)d_in[19];
  const float* f_w  = (const float*)d_in[20];
  const float* f_b  = (const float*)d_in[21];

  char* ws = (char*)d_ws;
  u16*  wqkT_I = (u16*)(ws + 0);          // [1024][512] bf16 ([wq_I|wk_I]^T)
  u16*  wqkT_M = (u16*)(ws + 1048576);    // [1024][512]
  u16*  fT     = (u16*)(ws + 2097152);    // [256][512]
  u16*  pcat   = (u16*)(ws + 2359296);    // [4][512][512] bf16 straight
  u16*  pfT    = (u16*)(ws + 4456448);    // [4][256][512] bf16 (131072 elems per slab)
  u16*  WT     = (u16*)(ws + 5505024);    // [8][256][2048] bf16
  float* cb    = (float*)(ws + 13893632); // [256]
  float* Araw  = (float*)(ws + 13894656); // [2][32768]
  float* rA    = (float*)(ws + 14156800); // [2][8]
  float* G     = (float*)(ws + 14157056); // [2][8][512]
  u16*  xIb    = (u16*)(ws + 14189824);   // [32768][512] bf16
  u16*  xMb    = (u16*)(ws + 47744256);
  u16*  qIb    = (u16*)(ws + 81298688);
  u16*  kIb    = (u16*)(ws + 114853120);
  u16*  kMb    = (u16*)(ws + 148407552);
  u16*  qMb    = xIb;                     // reuse: xIb dead once projI finishes

  // --- weight prep ---
  CArgs c;
  const float* csrc[6] = {x_I, x_M, p1_w, p2_w, p3_w, p4_w};
  u16* cdst[6] = {xIb, xMb, pcat, pcat + 262144, pcat + 524288, pcat + 786432};
  int ccnt[6] = {16777216, 16777216, 262144, 262144, 262144, 262144};
  for (int i = 0; i < 6; i++){ c.src[i] = csrc[i]; c.dst[i] = cdst[i]; c.cnt[i] = ccnt[i]; }
  convert_k<<<dim3(8192,1,6), 256, 0, stream>>>(c);

  TArgs t;
  const float* tsrc[5] = {wq_I, wk_I, wq_M, wk_M, f_w};
  u16* tdst[5] = {wqkT_I, wqkT_I + 262144, wqkT_M, wqkT_M + 262144, fT};
  int tnc[5] = {512, 512, 512, 512, 256};
  for (int i = 0; i < 5; i++){ t.src[i] = tsrc[i]; t.dst[i] = tdst[i]; t.ncol[i] = tnc[i]; }
  transpose_k<<<dim3(8,8,5), 256, 0, stream>>>(t);

  cbias_k<<<1, 256, 0, stream>>>(p1_b, p2_b, p3_b, p4_b, f_w, f_b, cb);

  // pfT_i[o][d] = sum_j f_w[j][o] p_i[d][j]   (M=256, N=512, K=512)
  for (int i = 0; i < 4; i++)
    gemm2_k<1><<<dim3(2,4), 256, 0, stream>>>(fT, nullptr, nullptr, nullptr,
        pcat + i*262144, nullptr, nullptr, nullptr, pfT + i*131072, nullptr, nullptr);

  // --- projections: [q|k] = x @ [wq|wk], raw (pre-norm) ---
  gemm2_k<0><<<dim3(256,8), 256, 0, stream>>>(xIb, nullptr, nullptr, nullptr,
      wqkT_I, bq_I, bk_I, nullptr, qIb, kIb, nullptr);
  gemm2_k<0><<<dim3(256,8), 256, 0, stream>>>(xMb, nullptr, nullptr, nullptr,
      wqkT_M, bq_M, bk_M, nullptr, qMb, kMb, nullptr);

  rownorm_k<<<dim3(8192,4), 256, 0, stream>>>(qIb, kIb, qMb, kMb, wg_I, wg_M, Araw);
  anorm_k<<<dim3(8,2), 256, 0, stream>>>(Araw, rA, G);
  gcalc_k<<<dim3(16,8,2), 256, 0, stream>>>(qIb, qMb, Araw, rA, G);

  weff_k<<<dim3(8,256), 256, 0, stream>>>(pfT, fT, G, WT);

  // --- final: out = [kI|kM|qI|qM] @ WT[b]^T + cb ---
  gemm2_k<2><<<dim3(256,2), 256, 0, stream>>>(kIb, kMb, qIb, qMb,
      WT, nullptr, nullptr, cb, nullptr, nullptr, (float*)d_out);
}

// Round 5
// 421.337 us; speedup vs baseline: 1.8438x; 1.1856x over previous
//
#include <hip/hip_runtime.h>

typedef unsigned short u16;
typedef unsigned int   u32;
typedef __bf16 bf16_t;
typedef bf16_t bf16x8 __attribute__((ext_vector_type(8)));
typedef float  f32x4  __attribute__((ext_vector_type(4)));

__device__ __forceinline__ float b2f(u16 u){
  u32 x = ((u32)u) << 16;
  return __builtin_bit_cast(float, x);
}
__device__ __forceinline__ u16 f2b(float f){
  u32 u = __builtin_bit_cast(u32, f);
  u32 r = u + 0x7FFFu + ((u >> 16) & 1u);   // round-to-nearest-even
  return (u16)(r >> 16);
}

union V8 { uint4 q; u16 u[8]; };

// async global(16B/lane) -> LDS. dst wave-uniform; lane l lands at dst + l*16B.
__device__ __forceinline__ void gld16(const u16* gsrc, u16* ldst){
  __builtin_amdgcn_global_load_lds(
      (const __attribute__((address_space(1))) u32*)gsrc,
      (__attribute__((address_space(3))) u32*)ldst, 16, 0, 0);
}

// ---------- straight f32 -> bf16 convert (x_I, x_M, p1..p4) ----------
struct CArgs { const float* src[6]; u16* dst[6]; int cnt[6]; };

__global__ __launch_bounds__(256) void convert_k(CArgs c){
  int z = blockIdx.z;
  int i8 = (blockIdx.x * 256 + threadIdx.x) * 8;
  if (i8 >= c.cnt[z]) return;
  const float* s = c.src[z] + i8;
  float4 a = *(const float4*)s;
  float4 b = *(const float4*)(s + 4);
  V8 o;
  o.u[0]=f2b(a.x); o.u[1]=f2b(a.y); o.u[2]=f2b(a.z); o.u[3]=f2b(a.w);
  o.u[4]=f2b(b.x); o.u[5]=f2b(b.y); o.u[6]=f2b(b.z); o.u[7]=f2b(b.w);
  *(uint4*)(c.dst[z] + i8) = o.q;
}

// ---------- transpose (z<5) + cbias/G-zero (z==5) ----------
struct TArgs { const float* src[5]; u16* dst[5]; int ncol[5]; };

__global__ __launch_bounds__(256) void transpose_k(TArgs t,
    const float* __restrict__ p1b, const float* __restrict__ p2b,
    const float* __restrict__ p3b, const float* __restrict__ p4b,
    const float* __restrict__ fw, const float* __restrict__ fb,
    float* __restrict__ cb, float* __restrict__ G)
{
  __shared__ u16 T[64][65];
  __shared__ float sb[512];
  int z = blockIdx.z;
  int tid = threadIdx.x;
  if (z == 5){
    if (blockIdx.x == 0 && blockIdx.y == 0){
      // cb[o] = (p1_b+p2_b+p3_b+p4_b) @ f_w + f_b
      sb[tid]       = p1b[tid] + p2b[tid] + p3b[tid] + p4b[tid];
      sb[tid + 256] = p1b[tid+256] + p2b[tid+256] + p3b[tid+256] + p4b[tid+256];
      __syncthreads();
      float acc = 0.f;
      for (int j = 0; j < 512; j++) acc += sb[j] * fw[j*256 + tid];
      cb[tid] = acc + fb[tid];
    } else if (blockIdx.x >= 1 && blockIdx.x <= 4){
      int idx = ((blockIdx.x - 1)*8 + blockIdx.y)*256 + tid;
      G[idx] = 0.f;    // G is [2][8][512] = 8192 f32
    }
    return;
  }
  int nc = t.ncol[z];
  int j0 = blockIdx.y * 64;
  if (j0 >= nc) return;
  int i0 = blockIdx.x * 64;
  const float* s = t.src[z];
  u16* d = t.dst[z];
  #pragma unroll
  for (int rep = 0; rep < 16; rep++){
    int lin = rep*256 + tid;
    int r = lin >> 6, c = lin & 63;
    T[c][r] = f2b(s[(size_t)(i0 + r) * nc + j0 + c]);
  }
  __syncthreads();
  #pragma unroll
  for (int rep = 0; rep < 16; rep++){
    int lin = rep*256 + tid;
    int r = lin >> 6, c = lin & 63;
    d[(size_t)(j0 + r) * 512 + i0 + c] = T[r][c];
  }
}

// ------------- fused projection + bias + row-l2norm + Araw -------------
// grid (512, 2): x = 64-row m-block, y: 0 = q (writes Q, Araw), 1 = k (writes Kn)
// Block: 256 threads (4 waves), each wave 64 rows x 128 cols; acc 4x8 tiles.
__global__ __launch_bounds__(256, 2) void proj_k(
    const u16* __restrict__ X,        // [32768][512] bf16
    const u16* __restrict__ WT,       // [1024][512] bf16: rows 0-511 wq^T, 512-1023 wk^T
    const float* __restrict__ bq, const float* __restrict__ bk,
    const float* __restrict__ wg,     // [512] f32
    u16* __restrict__ Q, u16* __restrict__ Kn,
    float* __restrict__ Araw, int wsel)
{
  const int tid = threadIdx.x, l = tid & 63, w = tid >> 6;
  const int m0 = blockIdx.x * 64;
  const int y  = blockIdx.y;
  __shared__ __align__(16) u16 As[64*32];    // 4 KB
  __shared__ __align__(16) u16 Bs[512*32];   // 32 KB
  const int lr = l & 15, quad = l >> 4;
  const int srow = l >> 2, scol = (l & 3) * 8;
  const int wn = w * 128;
  const u16* Wbase = WT + (size_t)y * 512 * 512;

  f32x4 acc[4][8] = {};
  for (int k0 = 0; k0 < 512; k0 += 32){
    __syncthreads();
    gld16(X + (size_t)(m0 + w*16 + srow)*512 + k0 + scol, &As[w*512]);
    #pragma unroll
    for (int i = 0; i < 8; i++)
      gld16(Wbase + (size_t)(wn + i*16 + srow)*512 + k0 + scol, &Bs[(w*8 + i)*512]);
    __syncthreads();
    bf16x8 aF[4], bF[8];
    #pragma unroll
    for (int mt = 0; mt < 4; mt++)
      aF[mt] = *(const bf16x8*)&As[(mt*16 + lr)*32 + quad*8];
    #pragma unroll
    for (int nt = 0; nt < 8; nt++)
      bF[nt] = *(const bf16x8*)&Bs[(wn + nt*16 + lr)*32 + quad*8];
    #pragma unroll
    for (int mt = 0; mt < 4; mt++){
      #pragma unroll
      for (int nt = 0; nt < 8; nt++)
        acc[mt][nt] = __builtin_amdgcn_mfma_f32_16x16x32_bf16(aF[mt], bF[nt], acc[mt][nt], 0, 0, 0);
    }
  }

  // ---- epilogue: bias, per-row sumsq (+ wg dot for q), normalize, store ----
  const float* bias = y ? bk : bq;
  float wgv[8];
  if (y == 0){
    #pragma unroll
    for (int nt = 0; nt < 8; nt++) wgv[nt] = wg[wn + nt*16 + lr];
  }
  #pragma unroll
  for (int nt = 0; nt < 8; nt++){
    float bcol = bias[wn + nt*16 + lr];
    #pragma unroll
    for (int mt = 0; mt < 4; mt++)
      #pragma unroll
      for (int r = 0; r < 4; r++)
        acc[mt][nt][r] += bcol;
  }
  // per-(row) partials over this wave's 128 cols
  float ss[4][4], dq[4][4];
  #pragma unroll
  for (int mt = 0; mt < 4; mt++)
    #pragma unroll
    for (int r = 0; r < 4; r++){
      float s = 0.f, d = 0.f;
      #pragma unroll
      for (int nt = 0; nt < 8; nt++){
        float v = acc[mt][nt][r];
        s += v*v;
        if (y == 0) d += v * wgv[nt];
      }
      ss[mt][r] = s; dq[mt][r] = d;
    }
  // butterfly over the 16 lr lanes (xor 1,2,4,8 stays within quad-group)
  #pragma unroll
  for (int off = 1; off < 16; off <<= 1){
    #pragma unroll
    for (int mt = 0; mt < 4; mt++)
      #pragma unroll
      for (int r = 0; r < 4; r++){
        ss[mt][r] += __shfl_xor(ss[mt][r], off, 64);
        if (y == 0) dq[mt][r] += __shfl_xor(dq[mt][r], off, 64);
      }
  }
  __syncthreads();                 // all waves done reading As -> reuse as f32 scratch
  float* red  = (float*)As;        // [4][64] sumsq partials
  float* red2 = red + 256;         // [4][64] dot partials
  float* rnS  = red2 + 256;        // [64] 1/norm   (576 f32 <= 1024 f32 capacity)
  if (lr == 0){
    #pragma unroll
    for (int mt = 0; mt < 4; mt++)
      #pragma unroll
      for (int r = 0; r < 4; r++){
        int row = mt*16 + quad*4 + r;
        red[w*64 + row] = ss[mt][r];
        if (y == 0) red2[w*64 + row] = dq[mt][r];
      }
  }
  __syncthreads();
  if (tid < 64){
    float t2 = red[tid] + red[64+tid] + red[128+tid] + red[192+tid];
    float rn = 1.f / fmaxf(sqrtf(t2), 1e-12f);
    rnS[tid] = rn;
    if (y == 0){
      float d = red2[tid] + red2[64+tid] + red2[128+tid] + red2[192+tid];
      Araw[wsel*32768 + m0 + tid] = d * rn * 0.0625f;   // SCALE = 1/16
    }
  }
  __syncthreads();
  u16* OUT = y ? Kn : Q;
  #pragma unroll
  for (int mt = 0; mt < 4; mt++){
    f32x4 rn4 = *(const f32x4*)&rnS[mt*16 + quad*4];
    #pragma unroll
    for (int nt = 0; nt < 8; nt++){
      int col = wn + nt*16 + lr;
      #pragma unroll
      for (int r = 0; r < 4; r++)
        OUT[(size_t)(m0 + mt*16 + quad*4 + r)*512 + col] = f2b(acc[mt][nt][r] * rn4[r]);
    }
  }
}

// ------------- MFMA GEMM, 128x128 tile, BK=32, global_load_lds staging -------------
// MODE 1 (SMALL): C = A0 @ BT_z^T      K=512, N=512, z-batched over 4 slabs -> pfT (bf16)
// MODE 2 (FINAL): C = [kI|kM|qI|qM] @ WT[b]^T + cb  K=2048, N=256 -> Cf (f32)
template<int MODE>
__global__ __launch_bounds__(256) void gemm2_k(
    const u16* __restrict__ A0, const u16* __restrict__ A1,
    const u16* __restrict__ A2, const u16* __restrict__ A3,
    const u16* __restrict__ BT,
    const float* __restrict__ cb,
    u16* __restrict__ Cq, float* __restrict__ Cf)
{
  constexpr int KTOT = (MODE == 2) ? 2048 : 512;
  const int tid = threadIdx.x, l = tid & 63, w = tid >> 6;
  const int m0 = blockIdx.x * 128, n0 = blockIdx.y * 128;
  __shared__ u16 As[128*32];
  __shared__ u16 Bs[128*32];
  f32x4 acc[4][4] = {};
  const int wm = (w >> 1) * 64, wn = (w & 1) * 64;
  const int lr = l & 15, quad = l >> 4;
  const int srow = l >> 2, scol = (l & 3) * 8;

  const u16* Bbase = BT;
  u16* Cqb = Cq;
  if constexpr (MODE == 2)
    Bbase = BT + (size_t)(m0 >> 12) * 256 * 2048;   // per-batch folded weights
  if constexpr (MODE == 1){
    Bbase = BT + (size_t)blockIdx.z * 262144;       // pcat slab
    Cqb   = Cq + (size_t)blockIdx.z * 131072;       // pfT slab
  }

  for (int k0 = 0; k0 < KTOT; k0 += 32){
    __syncthreads();
    const u16* Ab; int kloc;
    if constexpr (MODE == 2){
      int which = k0 >> 9; kloc = k0 & 511;
      Ab = (which == 0) ? A0 : (which == 1) ? A1 : (which == 2) ? A2 : A3;
    } else { Ab = A0; kloc = k0; }
    #pragma unroll
    for (int i = 0; i < 2; i++){
      int r = w*32 + i*16 + srow;
      gld16(Ab    + (size_t)(m0 + r) * 512  + kloc + scol, &As[(w*2 + i) * 512]);
      gld16(Bbase + (size_t)(n0 + r) * KTOT + k0   + scol, &Bs[(w*2 + i) * 512]);
    }
    __syncthreads();
    bf16x8 aF[4], bF[4];
    #pragma unroll
    for (int mt = 0; mt < 4; mt++)
      aF[mt] = *(const bf16x8*)&As[(wm + mt*16 + lr)*32 + quad*8];
    #pragma unroll
    for (int nt = 0; nt < 4; nt++)
      bF[nt] = *(const bf16x8*)&Bs[(wn + nt*16 + lr)*32 + quad*8];
    #pragma unroll
    for (int mt = 0; mt < 4; mt++){
      #pragma unroll
      for (int nt = 0; nt < 4; nt++)
        acc[mt][nt] = __builtin_amdgcn_mfma_f32_16x16x32_bf16(aF[mt], bF[nt], acc[mt][nt], 0, 0, 0);
    }
  }
  #pragma unroll
  for (int nt = 0; nt < 4; nt++){
    int col = n0 + wn + nt*16 + lr;
    #pragma unroll
    for (int mt = 0; mt < 4; mt++){
      int row0 = m0 + wm + mt*16 + quad*4;
      #pragma unroll
      for (int r = 0; r < 4; r++){
        int row = row0 + r;
        float v = acc[mt][nt][r];
        if constexpr (MODE == 1){
          Cqb[(size_t)row*512 + col] = f2b(v);
        } else {
          Cf[(size_t)row*256 + col] = v + cb[col];
        }
      }
    }
  }
}

// -------- G[b,d] = rA * sum_n Araw[b,n] * q[b,n,d], rA computed in-block --------
__global__ __launch_bounds__(256) void gcalc_k(const u16* __restrict__ qI, const u16* __restrict__ qM,
                                               const float* __restrict__ Araw,
                                               float* __restrict__ G){
  int chunk = blockIdx.x, b = blockIdx.y, wsel = blockIdx.z;
  int tid = threadIdx.x, l = tid & 63, w = tid >> 6;
  const u16* q = (wsel == 0) ? qI : qM;
  const float* A = Araw + wsel*32768 + b*4096;
  __shared__ float Ash[256];
  __shared__ float red[4];
  // inline rA: sumsq over the batch's 4096 Araw values
  float ssl = 0.f;
  for (int i = tid; i < 4096; i += 256){ float a = A[i]; ssl += a*a; }
  #pragma unroll
  for (int off = 32; off > 0; off >>= 1) ssl += __shfl_xor(ssl, off, 64);
  if (l == 0) red[w] = ssl;
  int n0 = chunk * 256;
  Ash[tid] = A[n0 + tid];
  __syncthreads();
  float rA = 1.f / fmaxf(sqrtf(red[0] + red[1] + red[2] + red[3]), 1e-12f);
  const u16* qp = q + (size_t)(b*4096 + n0) * 512 + tid*2;
  float a0 = 0.f, a1 = 0.f;
  for (int n = 0; n < 256; n++){
    u32 pr = *(const u32*)(qp + (size_t)n * 512);
    float av = Ash[n];
    a0 += av * b2f((u16)(pr & 0xFFFF));
    a1 += av * b2f((u16)(pr >> 16));
  }
  atomicAdd(&G[(wsel*8 + b)*512 + tid*2],     a0 * rA);
  atomicAdd(&G[(wsel*8 + b)*512 + tid*2 + 1], a1 * rA);
}

// -------- WT[b][o][k]: k<512: G_I.pf1+G_M.pf4 (kI); <1024: G_I.pf2+G_M.pf3 (kM); else fT (qI+qM) --------
// pfT slabs are 256*512 = 131072 elements each.
__global__ __launch_bounds__(256) void weff_k(
    const u16* __restrict__ pfT, const u16* __restrict__ fT,
    const float* __restrict__ G, u16* __restrict__ WT)
{
  int b = blockIdx.x, o = blockIdx.y, tid = threadIdx.x;
  int k0 = tid * 8;
  V8 out;
  if (k0 < 1024){
    int kk = k0 & 511;
    const u16* pa = pfT + ((k0 < 512) ? 0      : 131072) + o*512 + kk;  // pf1 / pf2
    const u16* pb = pfT + ((k0 < 512) ? 393216 : 262144) + o*512 + kk;  // pf4 / pf3
    const float* gI = G + b*512 + kk;
    const float* gM = G + 4096 + b*512 + kk;
    V8 Pa, Pb; Pa.q = *(const uint4*)pa; Pb.q = *(const uint4*)pb;
    float4 gi0 = *(const float4*)gI, gi1 = *(const float4*)(gI+4);
    float4 gm0 = *(const float4*)gM, gm1 = *(const float4*)(gM+4);
    float gi[8] = {gi0.x,gi0.y,gi0.z,gi0.w,gi1.x,gi1.y,gi1.z,gi1.w};
    float gm[8] = {gm0.x,gm0.y,gm0.z,gm0.w,gm1.x,gm1.y,gm1.z,gm1.w};
    #pragma unroll
    for (int j = 0; j < 8; j++)
      out.u[j] = f2b(gi[j]*b2f(Pa.u[j]) + gm[j]*b2f(Pb.u[j]));
  } else {
    out.q = *(const uint4*)(fT + o*512 + (k0 & 511));
  }
  *(uint4*)(WT + ((size_t)b*256 + o)*2048 + k0) = out.q;
}

extern "C" void kernel_launch(void* const* d_in, const int* in_sizes, int n_in,
                              void* d_out, int out_size, void* d_ws, size_t ws_size,
                              hipStream_t stream)
{
  const float* x_I  = (const float*)d_in[0];
  const float* x_M  = (const float*)d_in[1];
  const float* wq_I = (const float*)d_in[2];
  const float* bq_I = (const float*)d_in[3];
  const float* wk_I = (const float*)d_in[4];
  const float* bk_I = (const float*)d_in[5];
  const float* wq_M = (const float*)d_in[6];
  const float* bq_M = (const float*)d_in[7];
  const float* wk_M = (const float*)d_in[8];
  const float* bk_M = (const float*)d_in[9];
  const float* wg_I = (const float*)d_in[10];
  const float* wg_M = (const float*)d_in[11];
  const float* p1_w = (const float*)d_in[12];
  const float* p1_b = (const float*)d_in[13];
  const float* p2_w = (const float*)d_in[14];
  const float* p2_b = (const float*)d_in[15];
  const float* p3_w = (const float*)d_in[16];
  const float* p3_b = (const float*)d_in[17];
  const float* p4_w = (const float*)d_in[18];
  const float* p4_b = (const float*)d_in[19];
  const float* f_w  = (const float*)d_in[20];
  const float* f_b  = (const float*)d_in[21];

  char* ws = (char*)d_ws;
  u16*  wqkT_I = (u16*)(ws + 0);          // [1024][512] bf16 ([wq_I|wk_I]^T)
  u16*  wqkT_M = (u16*)(ws + 1048576);    // [1024][512]
  u16*  fT     = (u16*)(ws + 2097152);    // [256][512]
  u16*  pcat   = (u16*)(ws + 2359296);    // [4][512][512] bf16 straight
  u16*  pfT    = (u16*)(ws + 4456448);    // [4][256][512] bf16 (131072 elems/slab)
  u16*  WT     = (u16*)(ws + 5505024);    // [8][256][2048] bf16
  float* cb    = (float*)(ws + 13893632); // [256]
  float* Araw  = (float*)(ws + 13894656); // [2][32768]
  float* G     = (float*)(ws + 14157056); // [2][8][512]
  u16*  xIb    = (u16*)(ws + 14189824);   // [32768][512] bf16
  u16*  xMb    = (u16*)(ws + 47744256);
  u16*  qIb    = (u16*)(ws + 81298688);
  u16*  kIb    = (u16*)(ws + 114853120);
  u16*  kMb    = (u16*)(ws + 148407552);
  u16*  qMb    = xIb;                     // reuse: xIb dead once projI finishes

  // --- 1: f32->bf16 conversions ---
  CArgs c;
  const float* csrc[6] = {x_I, x_M, p1_w, p2_w, p3_w, p4_w};
  u16* cdst[6] = {xIb, xMb, pcat, pcat + 262144, pcat + 524288, pcat + 786432};
  int ccnt[6] = {16777216, 16777216, 262144, 262144, 262144, 262144};
  for (int i = 0; i < 6; i++){ c.src[i] = csrc[i]; c.dst[i] = cdst[i]; c.cnt[i] = ccnt[i]; }
  convert_k<<<dim3(8192,1,6), 256, 0, stream>>>(c);

  // --- 2: weight transposes + cbias + G zero ---
  TArgs t;
  const float* tsrc[5] = {wq_I, wk_I, wq_M, wk_M, f_w};
  u16* tdst[5] = {wqkT_I, wqkT_I + 262144, wqkT_M, wqkT_M + 262144, fT};
  int tnc[5] = {512, 512, 512, 512, 256};
  for (int i = 0; i < 5; i++){ t.src[i] = tsrc[i]; t.dst[i] = tdst[i]; t.ncol[i] = tnc[i]; }
  transpose_k<<<dim3(8,8,6), 256, 0, stream>>>(t, p1_b, p2_b, p3_b, p4_b, f_w, f_b, cb, G);

  // --- 3: pfT_i[o][d] = sum_j f_w[j][o] p_i[d][j]  (batched over 4 slabs) ---
  gemm2_k<1><<<dim3(2,4,4), 256, 0, stream>>>(fT, nullptr, nullptr, nullptr,
      pcat, nullptr, pfT, nullptr);

  // --- 4,5: fused projection + norm + Araw ---
  proj_k<<<dim3(512,2), 256, 0, stream>>>(xIb, wqkT_I, bq_I, bk_I, wg_I, qIb, kIb, Araw, 0);
  proj_k<<<dim3(512,2), 256, 0, stream>>>(xMb, wqkT_M, bq_M, bk_M, wg_M, qMb, kMb, Araw, 1);

  // --- 6: G accumulation (rA inline) ---
  gcalc_k<<<dim3(16,8,2), 256, 0, stream>>>(qIb, qMb, Araw, G);

  // --- 7: fold G into effective weights ---
  weff_k<<<dim3(8,256), 256, 0, stream>>>(pfT, fT, G, WT);

  // --- 8: out = [kI|kM|qI|qM] @ WT[b]^T + cb ---
  gemm2_k<2><<<dim3(256,2), 256, 0, stream>>>(kIb, kMb, qIb, qMb,
      WT, cb, nullptr, (float*)d_out);
}

// Round 6
// 397.003 us; speedup vs baseline: 1.9568x; 1.0613x over previous
//
#include <hip/hip_runtime.h>

typedef unsigned short u16;
typedef unsigned int   u32;
typedef __bf16 bf16_t;
typedef bf16_t bf16x8 __attribute__((ext_vector_type(8)));
typedef float  f32x4  __attribute__((ext_vector_type(4)));

__device__ __forceinline__ float b2f(u16 u){
  u32 x = ((u32)u) << 16;
  return __builtin_bit_cast(float, x);
}
__device__ __forceinline__ u16 f2b(float f){
  u32 u = __builtin_bit_cast(u32, f);
  u32 r = u + 0x7FFFu + ((u >> 16) & 1u);   // round-to-nearest-even
  return (u16)(r >> 16);
}

union V8 { uint4 q; u16 u[8]; };

// async global(16B/lane) -> LDS. dst wave-uniform; lane l lands at dst + l*16B.
__device__ __forceinline__ void gld16(const u16* gsrc, u16* ldst){
  __builtin_amdgcn_global_load_lds(
      (const __attribute__((address_space(1))) u32*)gsrc,
      (__attribute__((address_space(3))) u32*)ldst, 16, 0, 0);
}

// ---------- f32 -> bf16 convert (p1..p4 only now) ----------
struct CArgs { const float* src[4]; u16* dst[4]; int cnt[4]; };

__global__ __launch_bounds__(256) void convert_k(CArgs c){
  int z = blockIdx.z;
  int i8 = (blockIdx.x * 256 + threadIdx.x) * 8;
  if (i8 >= c.cnt[z]) return;
  const float* s = c.src[z] + i8;
  float4 a = *(const float4*)s;
  float4 b = *(const float4*)(s + 4);
  V8 o;
  o.u[0]=f2b(a.x); o.u[1]=f2b(a.y); o.u[2]=f2b(a.z); o.u[3]=f2b(a.w);
  o.u[4]=f2b(b.x); o.u[5]=f2b(b.y); o.u[6]=f2b(b.z); o.u[7]=f2b(b.w);
  *(uint4*)(c.dst[z] + i8) = o.q;
}

// ---------- transpose (z<5) + cbias/Gun-zero (z==5) ----------
struct TArgs { const float* src[5]; u16* dst[5]; int ncol[5]; };

__global__ __launch_bounds__(256) void transpose_k(TArgs t,
    const float* __restrict__ p1b, const float* __restrict__ p2b,
    const float* __restrict__ p3b, const float* __restrict__ p4b,
    const float* __restrict__ fw, const float* __restrict__ fb,
    float* __restrict__ cb, float* __restrict__ Gun)
{
  __shared__ u16 T[64][65];
  __shared__ float sb[512];
  int z = blockIdx.z;
  int tid = threadIdx.x;
  if (z == 5){
    if (blockIdx.x == 0 && blockIdx.y == 0){
      sb[tid]       = p1b[tid] + p2b[tid] + p3b[tid] + p4b[tid];
      sb[tid + 256] = p1b[tid+256] + p2b[tid+256] + p3b[tid+256] + p4b[tid+256];
      __syncthreads();
      float acc = 0.f;
      for (int j = 0; j < 512; j++) acc += sb[j] * fw[j*256 + tid];
      cb[tid] = acc + fb[tid];
    } else if (blockIdx.x >= 1 && blockIdx.x <= 4){
      int idx = ((blockIdx.x - 1)*8 + blockIdx.y)*256 + tid;
      Gun[idx] = 0.f;    // Gun is [2][8][512] = 8192 f32, must be zero each call
    }
    return;
  }
  int nc = t.ncol[z];
  int j0 = blockIdx.y * 64;
  if (j0 >= nc) return;
  int i0 = blockIdx.x * 64;
  const float* s = t.src[z];
  u16* d = t.dst[z];
  #pragma unroll
  for (int rep = 0; rep < 16; rep++){
    int lin = rep*256 + tid;
    int r = lin >> 6, c = lin & 63;
    T[c][r] = f2b(s[(size_t)(i0 + r) * nc + j0 + c]);
  }
  __syncthreads();
  #pragma unroll
  for (int rep = 0; rep < 16; rep++){
    int lin = rep*256 + tid;
    int r = lin >> 6, c = lin & 63;
    d[(size_t)(j0 + r) * 512 + i0 + c] = T[r][c];
  }
}

// ------------- fused projection + bias + row-l2norm + Araw + Gun accumulation -------------
// grid (512, 2, 2): x = 64-row m-block, y: 0=q (writes Q, Araw, Gun), 1=k; z: 0=I, 1=M.
// A-tile (x, f32) staged via registers with in-flight f32->bf16 convert; B via global_load_lds.
__global__ __launch_bounds__(256, 2) void proj_k(
    const float* __restrict__ XI, const float* __restrict__ XM,
    const u16* __restrict__ WTI, const u16* __restrict__ WTM,  // [1024][512]: rows 0-511 wq^T, 512-1023 wk^T
    const float* __restrict__ bqI, const float* __restrict__ bkI,
    const float* __restrict__ bqM, const float* __restrict__ bkM,
    const float* __restrict__ wgI, const float* __restrict__ wgM,
    u16* __restrict__ qI, u16* __restrict__ kI,
    u16* __restrict__ qM, u16* __restrict__ kM,
    float* __restrict__ Araw, float* __restrict__ Gun)
{
  const int tid = threadIdx.x, l = tid & 63, w = tid >> 6;
  const int m0 = blockIdx.x * 64;
  const int y  = blockIdx.y, zi = blockIdx.z;
  __shared__ __align__(16) u16 As[64*32];    // 4 KB bf16 (converted x)
  __shared__ __align__(16) u16 Bs[512*32];   // 32 KB bf16 (weights)
  const int lr = l & 15, quad = l >> 4;
  const int srow = l >> 2, scol = (l & 3) * 8;
  const int wn = w * 128;

  const float* X  = zi ? XM : XI;
  const u16* Wbase = (zi ? WTM : WTI) + (size_t)y * 512 * 512;
  const float* bias = y ? (zi ? bkM : bkI) : (zi ? bqM : bqI);
  const float* wg   = zi ? wgM : wgI;
  u16* OUT = y ? (zi ? kM : kI) : (zi ? qM : qI);

  // A staging map: lane l -> row w*16 + l/4, k-seg (l&3)*8 (8 f32 = 32B contiguous)
  const int arow = w*16 + (l >> 2);
  const int aks  = (l & 3) * 8;

  f32x4 acc[4][8] = {};
  for (int k0 = 0; k0 < 512; k0 += 32){
    __syncthreads();
    {
      const float* src = X + (size_t)(m0 + arow)*512 + k0 + aks;
      float4 p0 = *(const float4*)src;
      float4 p1 = *(const float4*)(src + 4);
      V8 o;
      o.u[0]=f2b(p0.x); o.u[1]=f2b(p0.y); o.u[2]=f2b(p0.z); o.u[3]=f2b(p0.w);
      o.u[4]=f2b(p1.x); o.u[5]=f2b(p1.y); o.u[6]=f2b(p1.z); o.u[7]=f2b(p1.w);
      *(uint4*)&As[arow*32 + aks] = o.q;   // byte offset = lane*16 within wave slab: conflict-free
    }
    #pragma unroll
    for (int i = 0; i < 8; i++)
      gld16(Wbase + (size_t)(wn + i*16 + srow)*512 + k0 + scol, &Bs[(w*8 + i)*512]);
    __syncthreads();
    bf16x8 aF[4], bF[8];
    #pragma unroll
    for (int mt = 0; mt < 4; mt++)
      aF[mt] = *(const bf16x8*)&As[(mt*16 + lr)*32 + quad*8];
    #pragma unroll
    for (int nt = 0; nt < 8; nt++)
      bF[nt] = *(const bf16x8*)&Bs[(wn + nt*16 + lr)*32 + quad*8];
    #pragma unroll
    for (int mt = 0; mt < 4; mt++){
      #pragma unroll
      for (int nt = 0; nt < 8; nt++)
        acc[mt][nt] = __builtin_amdgcn_mfma_f32_16x16x32_bf16(aF[mt], bF[nt], acc[mt][nt], 0, 0, 0);
    }
  }

  // ---- epilogue ----
  float wgv[8];
  if (y == 0){
    #pragma unroll
    for (int nt = 0; nt < 8; nt++) wgv[nt] = wg[wn + nt*16 + lr];
  }
  #pragma unroll
  for (int nt = 0; nt < 8; nt++){
    float bcol = bias[wn + nt*16 + lr];
    #pragma unroll
    for (int mt = 0; mt < 4; mt++)
      #pragma unroll
      for (int r = 0; r < 4; r++)
        acc[mt][nt][r] += bcol;
  }
  float ss[4][4], dq[4][4];
  #pragma unroll
  for (int mt = 0; mt < 4; mt++)
    #pragma unroll
    for (int r = 0; r < 4; r++){
      float s = 0.f, d = 0.f;
      #pragma unroll
      for (int nt = 0; nt < 8; nt++){
        float v = acc[mt][nt][r];
        s += v*v;
        if (y == 0) d += v * wgv[nt];
      }
      ss[mt][r] = s; dq[mt][r] = d;
    }
  #pragma unroll
  for (int off = 1; off < 16; off <<= 1){
    #pragma unroll
    for (int mt = 0; mt < 4; mt++)
      #pragma unroll
      for (int r = 0; r < 4; r++){
        ss[mt][r] += __shfl_xor(ss[mt][r], off, 64);
        if (y == 0) dq[mt][r] += __shfl_xor(dq[mt][r], off, 64);
      }
  }
  __syncthreads();                 // As dead -> reuse as f32 scratch
  float* red    = (float*)As;      // [4][64]
  float* red2   = red + 256;       // [4][64]
  float* rnS    = red2 + 256;      // [64]
  float* araw_s = rnS + 64;        // [64]
  if (lr == 0){
    #pragma unroll
    for (int mt = 0; mt < 4; mt++)
      #pragma unroll
      for (int r = 0; r < 4; r++){
        int row = mt*16 + quad*4 + r;
        red[w*64 + row] = ss[mt][r];
        if (y == 0) red2[w*64 + row] = dq[mt][r];
      }
  }
  __syncthreads();
  if (tid < 64){
    float t2 = red[tid] + red[64+tid] + red[128+tid] + red[192+tid];
    float rn = 1.f / fmaxf(sqrtf(t2), 1e-12f);
    rnS[tid] = rn;
    if (y == 0){
      float d = red2[tid] + red2[64+tid] + red2[128+tid] + red2[192+tid];
      float a = d * rn * 0.0625f;               // SCALE = 1/16
      araw_s[tid] = a;
      Araw[zi*32768 + m0 + tid] = a;
    }
  }
  __syncthreads();
  float part[8] = {};
  #pragma unroll
  for (int mt = 0; mt < 4; mt++){
    f32x4 rn4 = *(const f32x4*)&rnS[mt*16 + quad*4];
    #pragma unroll
    for (int r = 0; r < 4; r++){
      float aw = (y == 0) ? araw_s[mt*16 + quad*4 + r] : 0.f;
      #pragma unroll
      for (int nt = 0; nt < 8; nt++){
        float v = acc[mt][nt][r] * rn4[r];
        OUT[(size_t)(m0 + mt*16 + quad*4 + r)*512 + wn + nt*16 + lr] = f2b(v);
        if (y == 0) part[nt] += aw * v;
      }
    }
  }
  if (y == 0){
    #pragma unroll
    for (int nt = 0; nt < 8; nt++){
      part[nt] += __shfl_xor(part[nt], 16, 64);
      part[nt] += __shfl_xor(part[nt], 32, 64);
    }
    if (quad == 0){
      int bb = blockIdx.x >> 6;   // 64 rows/block, 4096 rows/batch
      #pragma unroll
      for (int nt = 0; nt < 8; nt++)
        atomicAdd(&Gun[((size_t)zi*8 + bb)*512 + wn + nt*16 + lr], part[nt]);
    }
  }
}

// ------------- MFMA GEMM, 128x128 tile, BK=32, global_load_lds staging -------------
// MODE 1 (SMALL): C = A0 @ BT_z^T      K=512, N=512, z-batched over 4 slabs -> pfT (bf16)
// MODE 2 (FINAL): C = [kI|kM|qI|qM] @ WT[b]^T + cb  K=2048, N=256 -> Cf (f32)
template<int MODE>
__global__ __launch_bounds__(256) void gemm2_k(
    const u16* __restrict__ A0, const u16* __restrict__ A1,
    const u16* __restrict__ A2, const u16* __restrict__ A3,
    const u16* __restrict__ BT,
    const float* __restrict__ cb,
    u16* __restrict__ Cq, float* __restrict__ Cf)
{
  constexpr int KTOT = (MODE == 2) ? 2048 : 512;
  const int tid = threadIdx.x, l = tid & 63, w = tid >> 6;
  const int m0 = blockIdx.x * 128, n0 = blockIdx.y * 128;
  __shared__ u16 As[128*32];
  __shared__ u16 Bs[128*32];
  f32x4 acc[4][4] = {};
  const int wm = (w >> 1) * 64, wn = (w & 1) * 64;
  const int lr = l & 15, quad = l >> 4;
  const int srow = l >> 2, scol = (l & 3) * 8;

  const u16* Bbase = BT;
  u16* Cqb = Cq;
  if constexpr (MODE == 2)
    Bbase = BT + (size_t)(m0 >> 12) * 256 * 2048;   // per-batch folded weights
  if constexpr (MODE == 1){
    Bbase = BT + (size_t)blockIdx.z * 262144;       // pcat slab
    Cqb   = Cq + (size_t)blockIdx.z * 131072;       // pfT slab
  }

  for (int k0 = 0; k0 < KTOT; k0 += 32){
    __syncthreads();
    const u16* Ab; int kloc;
    if constexpr (MODE == 2){
      int which = k0 >> 9; kloc = k0 & 511;
      Ab = (which == 0) ? A0 : (which == 1) ? A1 : (which == 2) ? A2 : A3;
    } else { Ab = A0; kloc = k0; }
    #pragma unroll
    for (int i = 0; i < 2; i++){
      int r = w*32 + i*16 + srow;
      gld16(Ab    + (size_t)(m0 + r) * 512  + kloc + scol, &As[(w*2 + i) * 512]);
      gld16(Bbase + (size_t)(n0 + r) * KTOT + k0   + scol, &Bs[(w*2 + i) * 512]);
    }
    __syncthreads();
    bf16x8 aF[4], bF[4];
    #pragma unroll
    for (int mt = 0; mt < 4; mt++)
      aF[mt] = *(const bf16x8*)&As[(wm + mt*16 + lr)*32 + quad*8];
    #pragma unroll
    for (int nt = 0; nt < 4; nt++)
      bF[nt] = *(const bf16x8*)&Bs[(wn + nt*16 + lr)*32 + quad*8];
    #pragma unroll
    for (int mt = 0; mt < 4; mt++){
      #pragma unroll
      for (int nt = 0; nt < 4; nt++)
        acc[mt][nt] = __builtin_amdgcn_mfma_f32_16x16x32_bf16(aF[mt], bF[nt], acc[mt][nt], 0, 0, 0);
    }
  }
  #pragma unroll
  for (int nt = 0; nt < 4; nt++){
    int col = n0 + wn + nt*16 + lr;
    #pragma unroll
    for (int mt = 0; mt < 4; mt++){
      int row0 = m0 + wm + mt*16 + quad*4;
      #pragma unroll
      for (int r = 0; r < 4; r++){
        int row = row0 + r;
        float v = acc[mt][nt][r];
        if constexpr (MODE == 1){
          Cqb[(size_t)row*512 + col] = f2b(v);
        } else {
          Cf[(size_t)row*256 + col] = v + cb[col];
        }
      }
    }
  }
}

// -------- rA[i] = 1/max(||Araw_i||, eps), i = wsel*8 + b --------
__global__ __launch_bounds__(256) void ranorm_k(const float* __restrict__ Araw,
                                                float* __restrict__ rA){
  int idx = blockIdx.x;               // 0..15
  const float* A = Araw + idx*4096;
  int tid = threadIdx.x, l = tid & 63, w = tid >> 6;
  float ss = 0.f;
  for (int i = tid; i < 4096; i += 256){ float a = A[i]; ss += a*a; }
  #pragma unroll
  for (int off = 32; off > 0; off >>= 1) ss += __shfl_xor(ss, off, 64);
  __shared__ float red[4];
  if (l == 0) red[w] = ss;
  __syncthreads();
  if (tid == 0)
    rA[idx] = 1.f / fmaxf(sqrtf(red[0] + red[1] + red[2] + red[3]), 1e-12f);
}

// -------- WT[b][o][k]: k<512: G_I.pf1+G_M.pf4 (kI); <1024: G_I.pf2+G_M.pf3 (kM); else fT (qI+qM) --------
__global__ __launch_bounds__(256) void weff_k(
    const u16* __restrict__ pfT, const u16* __restrict__ fT,
    const float* __restrict__ Gun, const float* __restrict__ rA,
    u16* __restrict__ WT)
{
  int b = blockIdx.x, o = blockIdx.y, tid = threadIdx.x;
  int k0 = tid * 8;
  V8 out;
  if (k0 < 1024){
    int kk = k0 & 511;
    const u16* pa = pfT + ((k0 < 512) ? 0      : 131072) + o*512 + kk;  // pf1 / pf2
    const u16* pb = pfT + ((k0 < 512) ? 393216 : 262144) + o*512 + kk;  // pf4 / pf3
    float rI = rA[b], rM = rA[8 + b];
    const float* gI = Gun + b*512 + kk;
    const float* gM = Gun + 4096 + b*512 + kk;
    V8 Pa, Pb; Pa.q = *(const uint4*)pa; Pb.q = *(const uint4*)pb;
    float4 gi0 = *(const float4*)gI, gi1 = *(const float4*)(gI+4);
    float4 gm0 = *(const float4*)gM, gm1 = *(const float4*)(gM+4);
    float gi[8] = {gi0.x,gi0.y,gi0.z,gi0.w,gi1.x,gi1.y,gi1.z,gi1.w};
    float gm[8] = {gm0.x,gm0.y,gm0.z,gm0.w,gm1.x,gm1.y,gm1.z,gm1.w};
    #pragma unroll
    for (int j = 0; j < 8; j++)
      out.u[j] = f2b(rI*gi[j]*b2f(Pa.u[j]) + rM*gm[j]*b2f(Pb.u[j]));
  } else {
    out.q = *(const uint4*)(fT + o*512 + (k0 & 511));
  }
  *(uint4*)(WT + ((size_t)b*256 + o)*2048 + k0) = out.q;
}

extern "C" void kernel_launch(void* const* d_in, const int* in_sizes, int n_in,
                              void* d_out, int out_size, void* d_ws, size_t ws_size,
                              hipStream_t stream)
{
  const float* x_I  = (const float*)d_in[0];
  const float* x_M  = (const float*)d_in[1];
  const float* wq_I = (const float*)d_in[2];
  const float* bq_I = (const float*)d_in[3];
  const float* wk_I = (const float*)d_in[4];
  const float* bk_I = (const float*)d_in[5];
  const float* wq_M = (const float*)d_in[6];
  const float* bq_M = (const float*)d_in[7];
  const float* wk_M = (const float*)d_in[8];
  const float* bk_M = (const float*)d_in[9];
  const float* wg_I = (const float*)d_in[10];
  const float* wg_M = (const float*)d_in[11];
  const float* p1_w = (const float*)d_in[12];
  const float* p1_b = (const float*)d_in[13];
  const float* p2_w = (const float*)d_in[14];
  const float* p2_b = (const float*)d_in[15];
  const float* p3_w = (const float*)d_in[16];
  const float* p3_b = (const float*)d_in[17];
  const float* p4_w = (const float*)d_in[18];
  const float* p4_b = (const float*)d_in[19];
  const float* f_w  = (const float*)d_in[20];
  const float* f_b  = (const float*)d_in[21];

  char* ws = (char*)d_ws;
  u16*  wqkT_I = (u16*)(ws + 0);          // [1024][512] bf16
  u16*  wqkT_M = (u16*)(ws + 1048576);    // [1024][512]
  u16*  fT     = (u16*)(ws + 2097152);    // [256][512]
  u16*  pcat   = (u16*)(ws + 2359296);    // [4][512][512] bf16 straight
  u16*  pfT    = (u16*)(ws + 4456448);    // [4][256][512] bf16 (131072 elems/slab)
  u16*  WT     = (u16*)(ws + 5505024);    // [8][256][2048] bf16
  float* cb    = (float*)(ws + 13893632); // [256]
  float* Araw  = (float*)(ws + 13894656); // [2][32768]
  float* rA    = (float*)(ws + 14156800); // [16]
  float* Gun   = (float*)(ws + 14157056); // [2][8][512]
  u16*  qIb    = (u16*)(ws + 14189824);   // [32768][512] bf16 each
  u16*  kIb    = (u16*)(ws + 47744256);
  u16*  qMb    = (u16*)(ws + 81298688);
  u16*  kMb    = (u16*)(ws + 114853120);

  // --- 1: p1..p4 f32->bf16 ---
  CArgs c;
  const float* csrc[4] = {p1_w, p2_w, p3_w, p4_w};
  u16* cdst[4] = {pcat, pcat + 262144, pcat + 524288, pcat + 786432};
  for (int i = 0; i < 4; i++){ c.src[i] = csrc[i]; c.dst[i] = cdst[i]; c.cnt[i] = 262144; }
  convert_k<<<dim3(128,1,4), 256, 0, stream>>>(c);

  // --- 2: weight transposes + cbias + Gun zero ---
  TArgs t;
  const float* tsrc[5] = {wq_I, wk_I, wq_M, wk_M, f_w};
  u16* tdst[5] = {wqkT_I, wqkT_I + 262144, wqkT_M, wqkT_M + 262144, fT};
  int tnc[5] = {512, 512, 512, 512, 256};
  for (int i = 0; i < 5; i++){ t.src[i] = tsrc[i]; t.dst[i] = tdst[i]; t.ncol[i] = tnc[i]; }
  transpose_k<<<dim3(8,8,6), 256, 0, stream>>>(t, p1_b, p2_b, p3_b, p4_b, f_w, f_b, cb, Gun);

  // --- 3: pfT_i[o][d] = sum_j f_w[j][o] p_i[d][j] ---
  gemm2_k<1><<<dim3(2,4,4), 256, 0, stream>>>(fT, nullptr, nullptr, nullptr,
      pcat, nullptr, pfT, nullptr);

  // --- 4: fused projection + norm + Araw + Gun (both inputs, one launch) ---
  proj_k<<<dim3(512,2,2), 256, 0, stream>>>(x_I, x_M, wqkT_I, wqkT_M,
      bq_I, bk_I, bq_M, bk_M, wg_I, wg_M, qIb, kIb, qMb, kMb, Araw, Gun);

  // --- 5: rA ---
  ranorm_k<<<16, 256, 0, stream>>>(Araw, rA);

  // --- 6: fold G into effective weights ---
  weff_k<<<dim3(8,256), 256, 0, stream>>>(pfT, fT, Gun, rA, WT);

  // --- 7: out = [kI|kM|qI|qM] @ WT[b]^T + cb ---
  gemm2_k<2><<<dim3(256,2), 256, 0, stream>>>(kIb, kMb, qIb, qMb,
      WT, cb, nullptr, (float*)d_out);
}